// Round 4
// baseline (409.516 us; speedup 1.0000x reference)
//
#include <hip/hip_runtime.h>
#include <math.h>

// Problem constants
#define BB 8
#define TT 1024
#define CC 1024
#define HH 16
#define HKV 4
#define HD 64
#define MM (BB*TT)   // 8192
#define LOG2E 1.4426950408889634f

typedef __attribute__((ext_vector_type(8))) short bf16x8;
typedef __attribute__((ext_vector_type(4))) float f32x4;

__device__ __forceinline__ unsigned short f2b(float f){
    union{float f; unsigned int i;} u; u.f = f;
    unsigned int r = u.i + 0x7fffu + ((u.i>>16)&1u);
    return (unsigned short)(r>>16);
}

// async 16B global -> LDS (gfx950 global_load_lds_dwordx4)
#define GLD16(gp, lp) __builtin_amdgcn_global_load_lds( \
    (__attribute__((address_space(1))) void*)(gp), \
    (__attribute__((address_space(3))) void*)(lp), 16, 0, 0)

// ---------------- fp32 -> bf16 conversions ----------------------------------
__global__ __launch_bounds__(256) void cvt_f32_bf16(const float* __restrict__ in,
                                                    unsigned short* __restrict__ out,
                                                    int n4){
    int i = blockIdx.x*256 + threadIdx.x;
    if (i < n4){
        float4 f = ((const float4*)in)[i];
        ushort4 o;
        o.x = f2b(f.x); o.y = f2b(f.y); o.z = f2b(f.z); o.w = f2b(f.w);
        ((ushort4*)out)[i] = o;
    }
}

// weights: w_q (262144 f4) -> wqkvb[0..], w_kv (131072 f4) -> wqkvb+1048576,
//          w_c (262144 f4) -> wcb
__global__ __launch_bounds__(256) void cvt_w3(const float* __restrict__ w_q,
                                              const float* __restrict__ w_kv,
                                              const float* __restrict__ w_c,
                                              unsigned short* __restrict__ wqkvb,
                                              unsigned short* __restrict__ wcb){
    int i = blockIdx.x*256 + threadIdx.x;
    const float* src; unsigned short* dst; int off;
    if (i < 262144)      { src = w_q;  dst = wqkvb;           off = i; }
    else if (i < 393216) { src = w_kv; dst = wqkvb + 1048576; off = i - 262144; }
    else                 { src = w_c;  dst = wcb;             off = i - 393216; }
    float4 f = ((const float4*)src)[off];
    ushort4 o;
    o.x = f2b(f.x); o.y = f2b(f.y); o.z = f2b(f.z); o.w = f2b(f.w);
    ((ushort4*)dst)[off] = o;
}

// ---------------- bf16 MFMA GEMM: C = A(MxK) * Bt(NxK)^T, BK=64 -------------
// LDS layout XOR-swizzled via source permutation (GLD16 dst must be
// base+lane*16): LDS[row][c] holds global chunk c ^ (row&7).
__global__ __launch_bounds__(256) void gemm_bt(const unsigned short* __restrict__ A,
                                               const unsigned short* __restrict__ Bt,
                                               float* __restrict__ Cc,
                                               int M, int N, int K){
    __shared__ __align__(16) unsigned short As[128*64];
    __shared__ __align__(16) unsigned short Bs[128*64];
    const int tid  = threadIdx.x;
    const int wid  = tid >> 6;
    const int lane = tid & 63;
    const int wm   = wid >> 1;
    const int wn   = wid & 1;
    const int l16  = lane & 15;
    const int quad = lane >> 4;
    const int bm = blockIdx.y * 128;
    const int bn = blockIdx.x * 128;

    // staging: idx = it*256+tid; row = idx>>3 = it*32 + (tid>>3); c_lds = tid&7
    // source chunk cg = c_lds ^ (row&7)
    const unsigned short* ga[4]; const unsigned short* gb[4];
    char* la[4]; char* lb[4];
    {
        int rbase = tid >> 3, c_lds = tid & 7;
        #pragma unroll
        for (int it = 0; it < 4; ++it){
            int row = it*32 + rbase;
            int cg  = c_lds ^ (row & 7);
            ga[it] = A  + (size_t)(bm+row)*K + cg*8;
            gb[it] = Bt + (size_t)(bn+row)*K + cg*8;
            la[it] = (char*)As + (size_t)(it*256 + tid)*16;
            lb[it] = (char*)Bs + (size_t)(it*256 + tid)*16;
        }
    }

    f32x4 acc[4][4] = {};

    for (int k0 = 0; k0 < K; k0 += 64){
        __syncthreads();
        #pragma unroll
        for (int it = 0; it < 4; ++it){
            GLD16(ga[it] + k0, la[it]);
            GLD16(gb[it] + k0, lb[it]);
        }
        __syncthreads();

        #pragma unroll
        for (int kh = 0; kh < 2; ++kh){
            bf16x8 af[4], bfr[4];
            #pragma unroll
            for (int i = 0; i < 4; ++i){
                int row = wm*64 + i*16 + l16;
                int ch  = (kh*4 + quad) ^ (row & 7);
                af[i] = *(const bf16x8*)(As + row*64 + ch*8);
            }
            #pragma unroll
            for (int j = 0; j < 4; ++j){
                int row = wn*64 + j*16 + l16;
                int ch  = (kh*4 + quad) ^ (row & 7);
                bfr[j] = *(const bf16x8*)(Bs + row*64 + ch*8);
            }
            #pragma unroll
            for (int i = 0; i < 4; ++i)
                #pragma unroll
                for (int j = 0; j < 4; ++j)
                    acc[i][j] = __builtin_amdgcn_mfma_f32_16x16x32_bf16(af[i], bfr[j], acc[i][j], 0, 0, 0);
        }
    }

    #pragma unroll
    for (int i = 0; i < 4; ++i){
        int row0 = wm*64 + i*16 + quad*4;
        #pragma unroll
        for (int j = 0; j < 4; ++j){
            int col = bn + wn*64 + j*16 + l16;
            #pragma unroll
            for (int r = 0; r < 4; ++r){
                Cc[(size_t)(bm + row0 + r)*N + col] = acc[i][j][r];
            }
        }
    }
}

// ---------------- RMSNorm + RoPE + relayout (Q and K) -----------------------
// QKVf row stride 1536: Q at col 0..1023, K at 1024..1279, V at 1280..1535
__global__ __launch_bounds__(256) void norm_rope(const float* __restrict__ QKVf,
                                                 const float* __restrict__ qw,
                                                 const float* __restrict__ kw,
                                                 unsigned short* __restrict__ qa,
                                                 unsigned short* __restrict__ ka){
    int wid  = blockIdx.x*4 + (threadIdx.x >> 6);
    int lane = threadIdx.x & 63;
    int row  = wid / 20;
    int u    = wid - row*20;
    int b = row >> 10;
    int t = row & 1023;

    float val;
    const float* w;
    if (u < 16){ val = QKVf[(size_t)row*1536 + u*64 + lane];          w = qw; }
    else       { val = QKVf[(size_t)row*1536 + 1024 + (u-16)*64 + lane]; w = kw; }

    float ss = val*val;
    #pragma unroll
    for (int off = 32; off > 0; off >>= 1) ss += __shfl_xor(ss, off, 64);
    float normed = val * rsqrtf(ss*(1.0f/64.0f) + 1e-6f) * w[lane];

    int i = lane & 31;
    float freq = (float)t * exp2f(-(float)i * (13.287712379549449f/32.0f));
    float s, c;
    sincosf(freq, &s, &c);
    float other = __shfl_xor(normed, 32, 64);
    float outv = (lane < 32) ? (normed*c + other*s) : (-other*s + normed*c);

    if (u < 16){
        qa[(((size_t)(b*HH + u))*TT + t)*HD + lane] = f2b(outv);
    } else {
        ka[(((size_t)(b*HKV + (u-16)))*TT + t)*HD + lane] = f2b(outv);
    }
}

// ---------------- V transpose: QKVf fp32 -> vat bf16 (b,n,d,t) --------------
__global__ __launch_bounds__(256) void vtrans(const float* __restrict__ QKVf,
                                              unsigned short* __restrict__ vat){
    __shared__ float tile[64][65];
    const int tid = threadIdx.x;
    const int tblk = blockIdx.x, n = blockIdx.y, b = blockIdx.z;
    #pragma unroll
    for (int it = 0; it < 4; ++it){
        int fi = it*256 + tid;
        int r = fi >> 4, c4 = fi & 15;
        float4 v = *(const float4*)(QKVf + ((size_t)(b*TT + tblk*64 + r))*1536 + 1280 + n*64 + c4*4);
        tile[r][c4*4+0] = v.x; tile[r][c4*4+1] = v.y;
        tile[r][c4*4+2] = v.z; tile[r][c4*4+3] = v.w;
    }
    __syncthreads();
    const int d = tid >> 2, tseg = tid & 3;
    unsigned short tmp[16];
    #pragma unroll
    for (int i = 0; i < 16; ++i) tmp[i] = f2b(tile[tseg*16 + i][d]);
    size_t off = (((size_t)(b*HKV + n))*HD + d)*TT + tblk*64 + tseg*16;
    *(uint4*)(vat + off)     = *(const uint4*)tmp;
    *(uint4*)(vat + off + 8) = *(const uint4*)(tmp + 8);
}

// ---------------- Barrier-free flash attention ------------------------------
// Wave = (head, 16 q-rows). K/V loaded global->VGPR directly. 4 heads of one
// GQA group share a block for L1 locality. Fixed-cap softmax (cap<=50, causal
// diagonal guarantees row-max cap>=0): p = exp(cap-50) in [e^-100, 1].
__device__ __forceinline__ void attn_tile_body(
    bool masked, int k0, int qrow, int quad, int l16,
    const unsigned short* __restrict__ kb, const unsigned short* __restrict__ vb,
    bf16x8 qf0, bf16x8 qf1, unsigned short* __restrict__ PsW,
    float& lsum, f32x4* o)
{
    const float C1 = 0.125f * 0.04f * LOG2E;   // raw -> exponent of e^{2s/50}
    const float C2 = -100.0f * LOG2E;          // p = exp2(C2 * w)

    const unsigned short* kp = kb + (size_t)(k0 + l16)*HD + quad*8;
    bf16x8 kf0[4], kf1[4];
    #pragma unroll
    for (int j = 0; j < 4; ++j){
        kf0[j] = *(const bf16x8*)(kp + j*16*HD);
        kf1[j] = *(const bf16x8*)(kp + j*16*HD + 32);
    }
    #pragma unroll
    for (int j = 0; j < 4; ++j){
        f32x4 z = {};
        z = __builtin_amdgcn_mfma_f32_16x16x32_bf16(kf0[j], qf0, z, 0,0,0);
        z = __builtin_amdgcn_mfma_f32_16x16x32_bf16(kf1[j], qf1, z, 0,0,0);
        unsigned int pu[4];
        #pragma unroll
        for (int r = 0; r < 4; ++r){
            float e = exp2f(z[r]*C1);
            float w = __builtin_amdgcn_rcpf(e + 1.f);
            float p = exp2f(C2*w);
            if (masked && (k0 + j*16 + quad*4 + r > qrow)) p = 0.f;
            union{float f; unsigned int u;} cv; cv.f = p;
            unsigned int pt = cv.u & 0xffff0000u;     // truncate to bf16
            cv.u = pt;
            lsum += cv.f;                              // l consistent with P
            pu[r] = pt;
        }
        unsigned int pk0 = (pu[0] >> 16) | pu[1];
        unsigned int pk1 = (pu[2] >> 16) | pu[3];
        *(uint2*)(PsW + l16*72 + j*16 + quad*4) = make_uint2(pk0, pk1);
    }
    bf16x8 pf0 = *(const bf16x8*)(PsW + l16*72 + quad*8);
    bf16x8 pf1 = *(const bf16x8*)(PsW + l16*72 + quad*8 + 32);
    const unsigned short* vp = vb + (size_t)l16*TT + k0 + quad*8;
    #pragma unroll
    for (int jd = 0; jd < 4; ++jd){
        bf16x8 vf0 = *(const bf16x8*)(vp + jd*16*TT);
        bf16x8 vf1 = *(const bf16x8*)(vp + jd*16*TT + 32);
        o[jd] = __builtin_amdgcn_mfma_f32_16x16x32_bf16(pf0, vf0, o[jd], 0,0,0);
        o[jd] = __builtin_amdgcn_mfma_f32_16x16x32_bf16(pf1, vf1, o[jd], 0,0,0);
    }
}

__global__ __launch_bounds__(256) void attn_mfma(const unsigned short* __restrict__ qa,
                                                 const unsigned short* __restrict__ ka,
                                                 const unsigned short* __restrict__ vat,
                                                 unsigned short* __restrict__ ya){
    __shared__ __align__(16) unsigned short Ps[4][16*72];  // per-wave P buffer

    const int tid = threadIdx.x;
    const int wave = tid >> 6, lane = tid & 63;
    const int l16 = lane & 15, quad = lane >> 4;
    const int qrt = (gridDim.x - 1) - blockIdx.x;   // 0..63, heavy first
    const int n = blockIdx.y, b = blockIdx.z;
    const int h = n*4 + wave;                        // GQA group shares block
    const int qrow0 = qrt*16;
    const int qrow  = qrow0 + l16;

    const unsigned short* qptr = qa + (((size_t)(b*HH + h))*TT + qrow0 + l16)*HD + quad*8;
    bf16x8 qf0 = *(const bf16x8*)qptr;
    bf16x8 qf1 = *(const bf16x8*)(qptr + 32);

    const unsigned short* kb = ka  + ((size_t)(b*HKV + n))*TT*HD;
    const unsigned short* vb = vat + ((size_t)(b*HKV + n))*HD*TT;

    float lsum = 0.f;
    f32x4 o[4] = {};
    unsigned short* PsW = &Ps[wave][0];

    const int ntiles = qrt/4 + 1;
    for (int kt = 0; kt < ntiles-1; ++kt)
        attn_tile_body(false, kt*64, qrow, quad, l16, kb, vb, qf0, qf1, PsW, lsum, o);
    attn_tile_body(true, (ntiles-1)*64, qrow, quad, l16, kb, vb, qf0, qf1, PsW, lsum, o);

    // l reduction over quads (each quad handled a disjoint key subset)
    lsum += __shfl_xor(lsum, 16, 64);
    lsum += __shfl_xor(lsum, 32, 64);
    float inv = __builtin_amdgcn_rcpf(lsum);

    // epilogue: O C-layout (row=q=quad*4+r, col=d=jd*16+l16)
    #pragma unroll
    for (int r = 0; r < 4; ++r){
        float linv = __shfl(inv, (lane & 48) | (quad*4 + r), 64);
        int t = qrow0 + quad*4 + r;
        #pragma unroll
        for (int jd = 0; jd < 4; ++jd)
            ya[(((size_t)(b*TT + t))*HH + h)*HD + jd*16 + l16] = f2b(o[jd][r]*linv);
    }
}

// ---------------- launch ----------------------------------------------------
extern "C" void kernel_launch(void* const* d_in, const int* in_sizes, int n_in,
                              void* d_out, int out_size, void* d_ws, size_t ws_size,
                              hipStream_t stream) {
    const float* x    = (const float*)d_in[0];
    const float* w_q  = (const float*)d_in[1];
    const float* w_kv = (const float*)d_in[2];
    const float* w_c  = (const float*)d_in[3];
    const float* qw   = (const float*)d_in[4];
    const float* kw   = (const float*)d_in[5];
    float* out = (float*)d_out;

    char* ws = (char*)d_ws;
    unsigned short* xb    = (unsigned short*)(ws);                    // 16 MB
    unsigned short* wqkvb = (unsigned short*)(ws + ((size_t)16<<20)); // 3 MB
    unsigned short* wcb   = (unsigned short*)(ws + ((size_t)19<<20)); // 2 MB
    float*          QKVf  = (float*)(ws + ((size_t)21<<20));          // 48 MB
    unsigned short* qa    = (unsigned short*)(ws + ((size_t)69<<20)); // 16 MB
    unsigned short* ka    = (unsigned short*)(ws + ((size_t)85<<20)); // 4 MB
    unsigned short* vat   = (unsigned short*)(ws + ((size_t)89<<20)); // 4 MB
    unsigned short* ya    = (unsigned short*)(ws + ((size_t)93<<20)); // 16 MB

    // 1) convert inputs to bf16
    cvt_f32_bf16<<<dim3((MM*CC/4)/256), 256, 0, stream>>>(x, xb, MM*CC/4);
    cvt_w3<<<dim3(2560), 256, 0, stream>>>(w_q, w_kv, w_c, wqkvb, wcb);

    // 2) fused QKV = x @ [w_q; w_kv]^T  (8192 x 1536 x 1024)
    gemm_bt<<<dim3(1536/128, MM/128), 256, 0, stream>>>(xb, wqkvb, QKVf, MM, 1536, CC);

    // 3) V transpose to (b,n,d,t) bf16
    vtrans<<<dim3(TT/64, HKV, BB), 256, 0, stream>>>(QKVf, vat);

    // 4) RMSNorm + RoPE for Q,K
    norm_rope<<<dim3(MM*20/4), 256, 0, stream>>>(QKVf, qw, kw, qa, ka);

    // 5) barrier-free flash attention
    attn_mfma<<<dim3(64, HKV, BB), 256, 0, stream>>>(qa, ka, vat, ya);

    // 6) out = y @ w_c^T
    gemm_bt<<<dim3(CC/128, MM/128), 256, 0, stream>>>(ya, wcb, out, MM, CC, CC);
}

// Round 5
// 301.686 us; speedup vs baseline: 1.3574x; 1.3574x over previous
//
#include <hip/hip_runtime.h>
#include <math.h>

// Problem constants
#define BB 8
#define TT 1024
#define CC 1024
#define HH 16
#define HKV 4
#define HD 64
#define MM (BB*TT)   // 8192
#define LOG2E 1.4426950408889634f

typedef __attribute__((ext_vector_type(8))) short bf16x8;
typedef __attribute__((ext_vector_type(4))) float f32x4;

__device__ __forceinline__ float b2f(unsigned short x){
    union{unsigned int i; float f;} u; u.i = ((unsigned int)x)<<16; return u.f;
}
__device__ __forceinline__ unsigned short f2b(float f){
    union{float f; unsigned int i;} u; u.f = f;
    unsigned int r = u.i + 0x7fffu + ((u.i>>16)&1u);
    return (unsigned short)(r>>16);
}

// async 16B global -> LDS (gfx950 global_load_lds_dwordx4)
#define GLD16(gp, lp) __builtin_amdgcn_global_load_lds( \
    (__attribute__((address_space(1))) void*)(gp), \
    (__attribute__((address_space(3))) void*)(lp), 16, 0, 0)

// ---------------- fp32 -> bf16 conversions ----------------------------------
__global__ __launch_bounds__(256) void cvt_f32_bf16(const float* __restrict__ in,
                                                    unsigned short* __restrict__ out,
                                                    int n4){
    int i = blockIdx.x*256 + threadIdx.x;
    if (i < n4){
        float4 f = ((const float4*)in)[i];
        ushort4 o;
        o.x = f2b(f.x); o.y = f2b(f.y); o.z = f2b(f.z); o.w = f2b(f.w);
        ((ushort4*)out)[i] = o;
    }
}

__global__ __launch_bounds__(256) void cvt_w3(const float* __restrict__ w_q,
                                              const float* __restrict__ w_kv,
                                              const float* __restrict__ w_c,
                                              unsigned short* __restrict__ wqkvb,
                                              unsigned short* __restrict__ wcb){
    int i = blockIdx.x*256 + threadIdx.x;
    const float* src; unsigned short* dst; int off;
    if (i < 262144)      { src = w_q;  dst = wqkvb;           off = i; }
    else if (i < 393216) { src = w_kv; dst = wqkvb + 1048576; off = i - 262144; }
    else                 { src = w_c;  dst = wcb;             off = i - 393216; }
    float4 f = ((const float4*)src)[off];
    ushort4 o;
    o.x = f2b(f.x); o.y = f2b(f.y); o.z = f2b(f.z); o.w = f2b(f.w);
    ((ushort4*)dst)[off] = o;
}

// ---------------- bf16 MFMA GEMM: C = A(MxK) * Bt(NxK)^T, BK=64 -------------
// XOR-swizzled LDS (source-side permutation, GLD16 dst stays contiguous).
template<int BF16OUT>
__global__ __launch_bounds__(256) void gemm_bt(const unsigned short* __restrict__ A,
                                               const unsigned short* __restrict__ Bt,
                                               void* __restrict__ Cc,
                                               int M, int N, int K){
    __shared__ __align__(16) unsigned short As[128*64];
    __shared__ __align__(16) unsigned short Bs[128*64];
    const int tid  = threadIdx.x;
    const int wid  = tid >> 6;
    const int lane = tid & 63;
    const int wm   = wid >> 1;
    const int wn   = wid & 1;
    const int l16  = lane & 15;
    const int quad = lane >> 4;
    const int bm = blockIdx.y * 128;
    const int bn = blockIdx.x * 128;

    const unsigned short* ga[4]; const unsigned short* gb[4];
    char* la[4]; char* lb[4];
    {
        int rbase = tid >> 3, c_lds = tid & 7;
        #pragma unroll
        for (int it = 0; it < 4; ++it){
            int row = it*32 + rbase;
            int cg  = c_lds ^ (row & 7);
            ga[it] = A  + (size_t)(bm+row)*K + cg*8;
            gb[it] = Bt + (size_t)(bn+row)*K + cg*8;
            la[it] = (char*)As + (size_t)(it*256 + tid)*16;
            lb[it] = (char*)Bs + (size_t)(it*256 + tid)*16;
        }
    }

    f32x4 acc[4][4] = {};

    for (int k0 = 0; k0 < K; k0 += 64){
        __syncthreads();
        #pragma unroll
        for (int it = 0; it < 4; ++it){
            GLD16(ga[it] + k0, la[it]);
            GLD16(gb[it] + k0, lb[it]);
        }
        __syncthreads();

        #pragma unroll
        for (int kh = 0; kh < 2; ++kh){
            bf16x8 af[4], bfr[4];
            #pragma unroll
            for (int i = 0; i < 4; ++i){
                int row = wm*64 + i*16 + l16;
                int ch  = (kh*4 + quad) ^ (row & 7);
                af[i] = *(const bf16x8*)(As + row*64 + ch*8);
            }
            #pragma unroll
            for (int j = 0; j < 4; ++j){
                int row = wn*64 + j*16 + l16;
                int ch  = (kh*4 + quad) ^ (row & 7);
                bfr[j] = *(const bf16x8*)(Bs + row*64 + ch*8);
            }
            #pragma unroll
            for (int i = 0; i < 4; ++i)
                #pragma unroll
                for (int j = 0; j < 4; ++j)
                    acc[i][j] = __builtin_amdgcn_mfma_f32_16x16x32_bf16(af[i], bfr[j], acc[i][j], 0, 0, 0);
        }
    }

    #pragma unroll
    for (int i = 0; i < 4; ++i){
        int row0 = wm*64 + i*16 + quad*4;
        #pragma unroll
        for (int j = 0; j < 4; ++j){
            int col = bn + wn*64 + j*16 + l16;
            #pragma unroll
            for (int r = 0; r < 4; ++r){
                if (BF16OUT)
                    ((unsigned short*)Cc)[(size_t)(bm + row0 + r)*N + col] = f2b(acc[i][j][r]);
                else
                    ((float*)Cc)[(size_t)(bm + row0 + r)*N + col] = acc[i][j][r];
            }
        }
    }
}

// ---------------- RMSNorm + RoPE + relayout (Q and K), bf16 QKV input -------
// QKVb row stride 1536: Q cols 0..1023, K 1024..1279, V 1280..1535
__global__ __launch_bounds__(256) void norm_rope(const unsigned short* __restrict__ QKVb,
                                                 const float* __restrict__ qw,
                                                 const float* __restrict__ kw,
                                                 unsigned short* __restrict__ qa,
                                                 unsigned short* __restrict__ ka){
    int wid  = blockIdx.x*4 + (threadIdx.x >> 6);
    int lane = threadIdx.x & 63;
    int row  = wid / 20;
    int u    = wid - row*20;
    int b = row >> 10;
    int t = row & 1023;

    float val;
    const float* w;
    if (u < 16){ val = b2f(QKVb[(size_t)row*1536 + u*64 + lane]);            w = qw; }
    else       { val = b2f(QKVb[(size_t)row*1536 + 1024 + (u-16)*64 + lane]); w = kw; }

    float ss = val*val;
    #pragma unroll
    for (int off = 32; off > 0; off >>= 1) ss += __shfl_xor(ss, off, 64);
    float normed = val * rsqrtf(ss*(1.0f/64.0f) + 1e-6f) * w[lane];

    int i = lane & 31;
    float freq = (float)t * exp2f(-(float)i * (13.287712379549449f/32.0f));
    float s, c;
    sincosf(freq, &s, &c);
    float other = __shfl_xor(normed, 32, 64);
    float outv = (lane < 32) ? (normed*c + other*s) : (-other*s + normed*c);

    if (u < 16){
        qa[(((size_t)(b*HH + u))*TT + t)*HD + lane] = f2b(outv);
    } else {
        ka[(((size_t)(b*HKV + (u-16)))*TT + t)*HD + lane] = f2b(outv);
    }
}

// ---------------- V transpose: QKVb bf16 -> vat bf16 (b,n,d,t) --------------
__global__ __launch_bounds__(256) void vtrans(const unsigned short* __restrict__ QKVb,
                                              unsigned short* __restrict__ vat){
    __shared__ unsigned short tile[64][72];
    const int tid = threadIdx.x;
    const int tblk = blockIdx.x, n = blockIdx.y, b = blockIdx.z;
    #pragma unroll
    for (int it = 0; it < 2; ++it){
        int i = it*256 + tid;           // 0..511 chunks of 8 bf16
        int r = i >> 3, c = i & 7;
        uint4 v = *(const uint4*)(QKVb + ((size_t)(b*TT + tblk*64 + r))*1536 + 1280 + n*64 + c*8);
        *(uint4*)(&tile[r][c*8]) = v;
    }
    __syncthreads();
    const int d = tid >> 2, tseg = tid & 3;
    unsigned short tmp[16];
    #pragma unroll
    for (int i = 0; i < 16; ++i) tmp[i] = tile[tseg*16 + i][d];
    size_t off = (((size_t)(b*HKV + n))*HD + d)*TT + tblk*64 + tseg*16;
    *(uint4*)(vat + off)     = *(const uint4*)tmp;
    *(uint4*)(vat + off + 8) = *(const uint4*)(tmp + 8);
}

// ---------------- Flash attention: GQA-shared LDS staging -------------------
// Block (qb, n, b): 1024 threads = 16 waves = 4 heads x 4 q-subtiles of 16.
// K/V tile staged ONCE per block via global_load_lds (XOR-swizzled layout).
// Fixed-cap softmax (softcap bounds scores to (-50,50], causal diagonal
// guarantees row-max cap >= 0): p = exp(cap-50) in [e^-100, 1].
__global__ __launch_bounds__(1024) void attn_mfma(const unsigned short* __restrict__ qa,
                                                  const unsigned short* __restrict__ ka,
                                                  const unsigned short* __restrict__ vat,
                                                  unsigned short* __restrict__ ya){
    __shared__ __align__(16) unsigned short Ks[64*64];    // [key][chunk^(key&7)]
    __shared__ __align__(16) unsigned short Vts[64*64];   // [d][chunk^(d&7)]
    __shared__ __align__(16) unsigned short Ps[16][16*72];// per-wave [q][key]

    const int tid = threadIdx.x;
    const int wave = tid >> 6, lane = tid & 63;
    const int l16 = lane & 15, quad = lane >> 4;
    const int qb = 15 - blockIdx.x;            // heavy blocks first
    const int n = blockIdx.y, b = blockIdx.z;
    const int h = n*4 + (wave >> 2);           // 4 heads share the block
    const int qrow0 = qb*64 + (wave & 3)*16;
    const int qrow  = qrow0 + l16;

    // Q fragment (B operand): [n=q=l16][k=d=quad*8+j]
    const unsigned short* qptr = qa + (((size_t)(b*HH + h))*TT + qrow0 + l16)*HD + quad*8;
    bf16x8 qf0 = *(const bf16x8*)qptr;
    bf16x8 qf1 = *(const bf16x8*)(qptr + 32);

    const unsigned short* kbase = ka  + ((size_t)(b*HKV + n))*TT*HD;
    const unsigned short* vbase = vat + ((size_t)(b*HKV + n))*HD*TT;

    // staging: tid<512 -> Ks chunk tid; tid>=512 -> Vts chunk tid-512
    const unsigned short* gsrc;
    char* ldst;
    {
        int i = tid & 511;
        int row = i >> 3, slot = i & 7;
        int cg = slot ^ (row & 7);
        if (tid < 512){
            gsrc = kbase + (size_t)row*HD + cg*8;          // + k0*HD per tile
            ldst = (char*)Ks + (size_t)i*16;
        } else {
            gsrc = vbase + (size_t)row*TT + cg*8;          // + k0 per tile
            ldst = (char*)Vts + (size_t)i*16;
        }
    }

    float lsum = 0.f;
    f32x4 o[4] = {};
    unsigned short* PsW = &Ps[wave][0];

    const float C1 = 0.125f * 0.04f * LOG2E;   // raw -> exponent of e^{2s/50}
    const float C2 = -100.0f * LOG2E;          // p = exp2(C2 * w)
    const int sw = l16 & 7;

    for (int kt = 0; kt <= qb; ++kt){
        const int k0 = kt*64;
        __syncthreads();
        GLD16(gsrc + (tid < 512 ? (size_t)k0*HD : (size_t)k0), ldst);
        __syncthreads();

        if (k0 <= qrow0 + 15){
            // S^T = K Q^T : D[m=key][n=q]; key = j*16+quad*4+r, q = l16
            f32x4 sacc[4];
            #pragma unroll
            for (int j = 0; j < 4; ++j){
                const unsigned short* kr = Ks + (j*16 + l16)*64;
                bf16x8 kf0 = *(const bf16x8*)(kr + (quad ^ sw)*8);
                bf16x8 kf1 = *(const bf16x8*)(kr + ((quad+4) ^ sw)*8);
                f32x4 z = {};
                z = __builtin_amdgcn_mfma_f32_16x16x32_bf16(kf0, qf0, z, 0,0,0);
                sacc[j] = __builtin_amdgcn_mfma_f32_16x16x32_bf16(kf1, qf1, z, 0,0,0);
            }
            const bool full = (k0 + 63 <= qrow0);   // wave-uniform
            #pragma unroll
            for (int j = 0; j < 4; ++j){
                unsigned int pu[4];
                #pragma unroll
                for (int r = 0; r < 4; ++r){
                    float e = exp2f(sacc[j][r]*C1);
                    float w = __builtin_amdgcn_rcpf(e + 1.f);
                    float p = exp2f(C2*w);
                    if (!full && (k0 + j*16 + quad*4 + r > qrow)) p = 0.f;
                    union{float f; unsigned int u;} cv; cv.f = p;
                    unsigned int pt = cv.u & 0xffff0000u;   // truncate to bf16
                    cv.u = pt;
                    lsum += cv.f;                           // l consistent with P
                    pu[r] = pt;
                }
                unsigned int pk0 = (pu[0] >> 16) | pu[1];
                unsigned int pk1 = (pu[2] >> 16) | pu[3];
                *(uint2*)(PsW + l16*72 + j*16 + quad*4) = make_uint2(pk0, pk1);
            }
            // O += P V : A = P[q][key], B = Vt[d][key]
            bf16x8 pf0 = *(const bf16x8*)(PsW + l16*72 + quad*8);
            bf16x8 pf1 = *(const bf16x8*)(PsW + l16*72 + quad*8 + 32);
            #pragma unroll
            for (int jd = 0; jd < 4; ++jd){
                const unsigned short* vr = Vts + (jd*16 + l16)*64;
                bf16x8 vf0 = *(const bf16x8*)(vr + (quad ^ sw)*8);
                bf16x8 vf1 = *(const bf16x8*)(vr + ((quad+4) ^ sw)*8);
                o[jd] = __builtin_amdgcn_mfma_f32_16x16x32_bf16(pf0, vf0, o[jd], 0,0,0);
                o[jd] = __builtin_amdgcn_mfma_f32_16x16x32_bf16(pf1, vf1, o[jd], 0,0,0);
            }
        }
    }

    // l reduction over quads (each quad handled a disjoint key subset)
    lsum += __shfl_xor(lsum, 16, 64);
    lsum += __shfl_xor(lsum, 32, 64);
    float inv = __builtin_amdgcn_rcpf(lsum);

    // epilogue: O C-layout (row=q=quad*4+r, col=d=jd*16+l16)
    #pragma unroll
    for (int r = 0; r < 4; ++r){
        float linv = __shfl(inv, (lane & 48) | (quad*4 + r), 64);
        int t = qrow0 + quad*4 + r;
        #pragma unroll
        for (int jd = 0; jd < 4; ++jd)
            ya[(((size_t)(b*TT + t))*HH + h)*HD + jd*16 + l16] = f2b(o[jd][r]*linv);
    }
}

// ---------------- launch ----------------------------------------------------
extern "C" void kernel_launch(void* const* d_in, const int* in_sizes, int n_in,
                              void* d_out, int out_size, void* d_ws, size_t ws_size,
                              hipStream_t stream) {
    const float* x    = (const float*)d_in[0];
    const float* w_q  = (const float*)d_in[1];
    const float* w_kv = (const float*)d_in[2];
    const float* w_c  = (const float*)d_in[3];
    const float* qw   = (const float*)d_in[4];
    const float* kw   = (const float*)d_in[5];
    float* out = (float*)d_out;

    char* ws = (char*)d_ws;
    unsigned short* xb    = (unsigned short*)(ws);                    // 16 MB
    unsigned short* wqkvb = (unsigned short*)(ws + ((size_t)16<<20)); // 3 MB
    unsigned short* wcb   = (unsigned short*)(ws + ((size_t)19<<20)); // 2 MB
    unsigned short* QKVb  = (unsigned short*)(ws + ((size_t)21<<20)); // 24 MB
    unsigned short* qa    = (unsigned short*)(ws + ((size_t)45<<20)); // 16 MB
    unsigned short* ka    = (unsigned short*)(ws + ((size_t)61<<20)); // 4 MB
    unsigned short* vat   = (unsigned short*)(ws + ((size_t)65<<20)); // 4 MB
    unsigned short* ya    = (unsigned short*)(ws + ((size_t)69<<20)); // 16 MB

    // 1) convert inputs to bf16
    cvt_f32_bf16<<<dim3((MM*CC/4)/256), 256, 0, stream>>>(x, xb, MM*CC/4);
    cvt_w3<<<dim3(2560), 256, 0, stream>>>(w_q, w_kv, w_c, wqkvb, wcb);

    // 2) fused QKV = x @ [w_q; w_kv]^T  (8192 x 1536 x 1024), bf16 out
    gemm_bt<1><<<dim3(1536/128, MM/128), 256, 0, stream>>>(xb, wqkvb, (void*)QKVb, MM, 1536, CC);

    // 3) V transpose to (b,n,d,t) bf16
    vtrans<<<dim3(TT/64, HKV, BB), 256, 0, stream>>>(QKVb, vat);

    // 4) RMSNorm + RoPE for Q,K
    norm_rope<<<dim3(MM*20/4), 256, 0, stream>>>(QKVb, qw, kw, qa, ka);

    // 5) flash attention, GQA-shared staging
    attn_mfma<<<dim3(16, HKV, BB), 1024, 0, stream>>>(qa, ka, vat, ya);

    // 6) out = y @ w_c^T (fp32 out)
    gemm_bt<0><<<dim3(CC/128, MM/128), 256, 0, stream>>>(ya, wcb, (void*)out, MM, CC, CC);
}

// Round 6
// 270.683 us; speedup vs baseline: 1.5129x; 1.1145x over previous
//
#include <hip/hip_runtime.h>
#include <math.h>

// Problem constants
#define BB 8
#define TT 1024
#define CC 1024
#define HH 16
#define HKV 4
#define HD 64
#define MM (BB*TT)   // 8192
#define LOG2E 1.4426950408889634f

typedef __attribute__((ext_vector_type(8))) short bf16x8;
typedef __attribute__((ext_vector_type(4))) float f32x4;

__device__ __forceinline__ float b2f(unsigned short x){
    union{unsigned int i; float f;} u; u.i = ((unsigned int)x)<<16; return u.f;
}
__device__ __forceinline__ unsigned short f2b(float f){
    union{float f; unsigned int i;} u; u.f = f;
    unsigned int r = u.i + 0x7fffu + ((u.i>>16)&1u);
    return (unsigned short)(r>>16);
}

// async 16B global -> LDS (gfx950 global_load_lds_dwordx4)
#define GLD16(gp, lp) __builtin_amdgcn_global_load_lds( \
    (__attribute__((address_space(1))) void*)(gp), \
    (__attribute__((address_space(3))) void*)(lp), 16, 0, 0)

// ---------------- fp32 -> bf16 conversion (all inputs, one kernel) ----------
// x: 2097152 f4 chunks -> xb; w_q: 262144 -> wqkvb; w_kv: 131072 -> wqkvb+1M;
// w_c: 262144 -> wcb
__global__ __launch_bounds__(256) void cvt_all(const float* __restrict__ x,
                                               const float* __restrict__ w_q,
                                               const float* __restrict__ w_kv,
                                               const float* __restrict__ w_c,
                                               unsigned short* __restrict__ xb,
                                               unsigned short* __restrict__ wqkvb,
                                               unsigned short* __restrict__ wcb){
    int i = blockIdx.x*256 + threadIdx.x;
    const float* src; unsigned short* dst; int off;
    if (i < 2097152)      { src = x;    dst = xb;              off = i; }
    else if (i < 2359296) { src = w_q;  dst = wqkvb;           off = i - 2097152; }
    else if (i < 2490368) { src = w_kv; dst = wqkvb + 1048576; off = i - 2359296; }
    else                  { src = w_c;  dst = wcb;             off = i - 2490368; }
    float4 f = ((const float4*)src)[off];
    ushort4 o;
    o.x = f2b(f.x); o.y = f2b(f.y); o.z = f2b(f.z); o.w = f2b(f.w);
    ((ushort4*)dst)[off] = o;
}

// ---------------- bf16 MFMA GEMM: C = A(MxK) * Bt(NxK)^T, BK=64 -------------
// XOR-swizzled LDS (source-side permutation, GLD16 dst stays contiguous).
template<int BF16OUT>
__global__ __launch_bounds__(256) void gemm_bt(const unsigned short* __restrict__ A,
                                               const unsigned short* __restrict__ Bt,
                                               void* __restrict__ Cc,
                                               int M, int N, int K){
    __shared__ __align__(16) unsigned short As[128*64];
    __shared__ __align__(16) unsigned short Bs[128*64];
    const int tid  = threadIdx.x;
    const int wid  = tid >> 6;
    const int lane = tid & 63;
    const int wm   = wid >> 1;
    const int wn   = wid & 1;
    const int l16  = lane & 15;
    const int quad = lane >> 4;
    const int bm = blockIdx.y * 128;
    const int bn = blockIdx.x * 128;

    const unsigned short* ga[4]; const unsigned short* gb[4];
    char* la[4]; char* lb[4];
    {
        int rbase = tid >> 3, c_lds = tid & 7;
        #pragma unroll
        for (int it = 0; it < 4; ++it){
            int row = it*32 + rbase;
            int cg  = c_lds ^ (row & 7);
            ga[it] = A  + (size_t)(bm+row)*K + cg*8;
            gb[it] = Bt + (size_t)(bn+row)*K + cg*8;
            la[it] = (char*)As + (size_t)(it*256 + tid)*16;
            lb[it] = (char*)Bs + (size_t)(it*256 + tid)*16;
        }
    }

    f32x4 acc[4][4] = {};

    for (int k0 = 0; k0 < K; k0 += 64){
        __syncthreads();
        #pragma unroll
        for (int it = 0; it < 4; ++it){
            GLD16(ga[it] + k0, la[it]);
            GLD16(gb[it] + k0, lb[it]);
        }
        __syncthreads();

        #pragma unroll
        for (int kh = 0; kh < 2; ++kh){
            bf16x8 af[4], bfr[4];
            #pragma unroll
            for (int i = 0; i < 4; ++i){
                int row = wm*64 + i*16 + l16;
                int ch  = (kh*4 + quad) ^ (row & 7);
                af[i] = *(const bf16x8*)(As + row*64 + ch*8);
            }
            #pragma unroll
            for (int j = 0; j < 4; ++j){
                int row = wn*64 + j*16 + l16;
                int ch  = (kh*4 + quad) ^ (row & 7);
                bfr[j] = *(const bf16x8*)(Bs + row*64 + ch*8);
            }
            #pragma unroll
            for (int i = 0; i < 4; ++i)
                #pragma unroll
                for (int j = 0; j < 4; ++j)
                    acc[i][j] = __builtin_amdgcn_mfma_f32_16x16x32_bf16(af[i], bfr[j], acc[i][j], 0, 0, 0);
        }
    }

    #pragma unroll
    for (int i = 0; i < 4; ++i){
        int row0 = wm*64 + i*16 + quad*4;
        #pragma unroll
        for (int j = 0; j < 4; ++j){
            int col = bn + wn*64 + j*16 + l16;
            #pragma unroll
            for (int r = 0; r < 4; ++r){
                if (BF16OUT)
                    ((unsigned short*)Cc)[(size_t)(bm + row0 + r)*N + col] = f2b(acc[i][j][r]);
                else
                    ((float*)Cc)[(size_t)(bm + row0 + r)*N + col] = acc[i][j][r];
            }
        }
    }
}

// ---------------- RMSNorm + RoPE + relayout (Q and K), bf16 QKV input -------
// QKVb row stride 1536: Q cols 0..1023, K 1024..1279, V 1280..1535
__global__ __launch_bounds__(256) void norm_rope(const unsigned short* __restrict__ QKVb,
                                                 const float* __restrict__ qw,
                                                 const float* __restrict__ kw,
                                                 unsigned short* __restrict__ qa,
                                                 unsigned short* __restrict__ ka){
    int wid  = blockIdx.x*4 + (threadIdx.x >> 6);
    int lane = threadIdx.x & 63;
    int row  = wid / 20;
    int u    = wid - row*20;
    int b = row >> 10;
    int t = row & 1023;

    float val;
    const float* w;
    if (u < 16){ val = b2f(QKVb[(size_t)row*1536 + u*64 + lane]);            w = qw; }
    else       { val = b2f(QKVb[(size_t)row*1536 + 1024 + (u-16)*64 + lane]); w = kw; }

    float ss = val*val;
    #pragma unroll
    for (int off = 32; off > 0; off >>= 1) ss += __shfl_xor(ss, off, 64);
    float normed = val * rsqrtf(ss*(1.0f/64.0f) + 1e-6f) * w[lane];

    int i = lane & 31;
    float freq = (float)t * exp2f(-(float)i * (13.287712379549449f/32.0f));
    float s, c;
    sincosf(freq, &s, &c);
    float other = __shfl_xor(normed, 32, 64);
    float outv = (lane < 32) ? (normed*c + other*s) : (-other*s + normed*c);

    if (u < 16){
        qa[(((size_t)(b*HH + u))*TT + t)*HD + lane] = f2b(outv);
    } else {
        ka[(((size_t)(b*HKV + (u-16)))*TT + t)*HD + lane] = f2b(outv);
    }
}

// ---------------- V transpose: QKVb bf16 -> vat bf16 (b,n,d,t) --------------
__global__ __launch_bounds__(256) void vtrans(const unsigned short* __restrict__ QKVb,
                                              unsigned short* __restrict__ vat){
    __shared__ unsigned short tile[64][72];
    const int tid = threadIdx.x;
    const int tblk = blockIdx.x, n = blockIdx.y, b = blockIdx.z;
    #pragma unroll
    for (int it = 0; it < 2; ++it){
        int i = it*256 + tid;           // 0..511 chunks of 8 bf16
        int r = i >> 3, c = i & 7;
        uint4 v = *(const uint4*)(QKVb + ((size_t)(b*TT + tblk*64 + r))*1536 + 1280 + n*64 + c*8);
        *(uint4*)(&tile[r][c*8]) = v;
    }
    __syncthreads();
    const int d = tid >> 2, tseg = tid & 3;
    unsigned short tmp[16];
    #pragma unroll
    for (int i = 0; i < 16; ++i) tmp[i] = tile[tseg*16 + i][d];
    size_t off = (((size_t)(b*HKV + n))*HD + d)*TT + tblk*64 + tseg*16;
    *(uint4*)(vat + off)     = *(const uint4*)tmp;
    *(uint4*)(vat + off + 8) = *(const uint4*)(tmp + 8);
}

// ---------------- Flash attention: balanced pair-blocks ---------------------
// Block (i, n, b): 512 threads = 8 waves = 4 heads x 2 subtiles. Each wave
// owns TWO 16-row q-windows: rows of 32-row q-chunk i and of chunk 31-i.
// One K/V stream serves both windows + all 4 heads -> every block does
// exactly 68 half-tile-steps (uniform work; no tail imbalance).
// Fixed-cap softmax (softcap bounds scores to (-50,50], causal diagonal
// guarantees row-max cap >= 0): p = exp(cap-50) in [e^-100, 1].
__global__ __launch_bounds__(512, 4) void attn_mfma(const unsigned short* __restrict__ qa,
                                                    const unsigned short* __restrict__ ka,
                                                    const unsigned short* __restrict__ vat,
                                                    unsigned short* __restrict__ ya){
    __shared__ __align__(16) unsigned short Ks[64*64];    // [key][chunk^(key&7)]
    __shared__ __align__(16) unsigned short Vts[64*64];   // [d][chunk^(d&7)]
    __shared__ __align__(16) unsigned short Ps[8][32*72]; // per-wave [q32][key]

    const int tid = threadIdx.x;
    const int wave = tid >> 6, lane = tid & 63;
    const int l16 = lane & 15, quad = lane >> 4;
    const int ib = blockIdx.x;                 // 0..15, heavy (ktmax=15) first
    const int n = blockIdx.y, b = blockIdx.z;
    const int head = wave & 3, sub = wave >> 2;
    const int h = n*4 + head;
    const int R0_0 = ib*32 + sub*16;           // q-window A base row
    const int R0_1 = (31-ib)*32 + sub*16;      // q-window B base row

    // Q fragments (B operand): [n=q=l16][k=d=quad*8+j]
    bf16x8 qf[2][2];
    {
        const unsigned short* q0 = qa + (((size_t)(b*HH + h))*TT + R0_0 + l16)*HD + quad*8;
        const unsigned short* q1 = qa + (((size_t)(b*HH + h))*TT + R0_1 + l16)*HD + quad*8;
        qf[0][0] = *(const bf16x8*)q0; qf[0][1] = *(const bf16x8*)(q0 + 32);
        qf[1][0] = *(const bf16x8*)q1; qf[1][1] = *(const bf16x8*)(q1 + 32);
    }

    const unsigned short* kbase = ka  + ((size_t)(b*HKV + n))*TT*HD;
    const unsigned short* vbase = vat + ((size_t)(b*HKV + n))*HD*TT;

    // staging: each thread stages one 16B K chunk and one 16B V chunk
    const unsigned short* gk; const unsigned short* gv;
    char* lk; char* lv;
    {
        int row = tid >> 3, slot = tid & 7;
        int cg = slot ^ (row & 7);
        gk = kbase + (size_t)row*HD + cg*8;
        gv = vbase + (size_t)row*TT + cg*8;
        lk = (char*)Ks  + (size_t)tid*16;
        lv = (char*)Vts + (size_t)tid*16;
    }

    float lsum[2] = {0.f, 0.f};
    f32x4 o[2][4] = {};
    unsigned short* PsW = &Ps[wave][0];

    const float C1 = 0.125f * 0.04f * LOG2E;   // raw -> exponent of e^{2s/50}
    const float C2 = -100.0f * LOG2E;          // p = exp2(C2 * w)
    const int sw = l16 & 7;
    const int ktmax = (1023 - 32*ib) >> 6;

    for (int kt = 0; kt <= ktmax; ++kt){
        const int k0 = kt*64;
        __syncthreads();
        GLD16(gk + (size_t)k0*HD, lk);
        GLD16(gv + k0, lv);
        __syncthreads();

        const bool act0 = (k0 <= R0_0 + 15);
        // S^T = K Q^T : D[m=key][n=q]; key = j*16+quad*4+r, q = l16
        f32x4 sacc[2][4];
        #pragma unroll
        for (int j = 0; j < 4; ++j){
            const unsigned short* kr = Ks + (j*16 + l16)*64;
            bf16x8 kf0 = *(const bf16x8*)(kr + (quad ^ sw)*8);
            bf16x8 kf1 = *(const bf16x8*)(kr + ((quad+4) ^ sw)*8);
            if (act0){
                f32x4 z = {};
                z = __builtin_amdgcn_mfma_f32_16x16x32_bf16(kf0, qf[0][0], z, 0,0,0);
                sacc[0][j] = __builtin_amdgcn_mfma_f32_16x16x32_bf16(kf1, qf[0][1], z, 0,0,0);
            }
            {
                f32x4 z = {};
                z = __builtin_amdgcn_mfma_f32_16x16x32_bf16(kf0, qf[1][0], z, 0,0,0);
                sacc[1][j] = __builtin_amdgcn_mfma_f32_16x16x32_bf16(kf1, qf[1][1], z, 0,0,0);
            }
        }
        // softmax + P write per half
        #pragma unroll
        for (int h2 = 0; h2 < 2; ++h2){
            if (h2 == 0 && !act0) continue;
            const int Rb = (h2 == 0) ? R0_0 : R0_1;
            const bool full = (k0 + 63 <= Rb);
            const int qrow = Rb + l16;
            #pragma unroll
            for (int j = 0; j < 4; ++j){
                unsigned int pu[4];
                #pragma unroll
                for (int r = 0; r < 4; ++r){
                    float e = exp2f(sacc[h2][j][r]*C1);
                    float w = __builtin_amdgcn_rcpf(e + 1.f);
                    float p = exp2f(C2*w);
                    if (!full && (k0 + j*16 + quad*4 + r > qrow)) p = 0.f;
                    union{float f; unsigned int u;} cv; cv.f = p;
                    unsigned int pt = cv.u & 0xffff0000u;   // truncate to bf16
                    cv.u = pt;
                    lsum[h2] += cv.f;                       // l consistent with P
                    pu[r] = pt;
                }
                unsigned int pk0 = (pu[0] >> 16) | pu[1];
                unsigned int pk1 = (pu[2] >> 16) | pu[3];
                *(uint2*)(PsW + (h2*16 + l16)*72 + j*16 + quad*4) = make_uint2(pk0, pk1);
            }
        }
        // PV: A = P[q][key], B = Vt[d][key]; vf shared across both halves
        bf16x8 pf[2][2];
        if (act0){
            pf[0][0] = *(const bf16x8*)(PsW + l16*72 + quad*8);
            pf[0][1] = *(const bf16x8*)(PsW + l16*72 + quad*8 + 32);
        }
        pf[1][0] = *(const bf16x8*)(PsW + (16 + l16)*72 + quad*8);
        pf[1][1] = *(const bf16x8*)(PsW + (16 + l16)*72 + quad*8 + 32);
        #pragma unroll
        for (int jd = 0; jd < 4; ++jd){
            const unsigned short* vr = Vts + (jd*16 + l16)*64;
            bf16x8 vf0 = *(const bf16x8*)(vr + (quad ^ sw)*8);
            bf16x8 vf1 = *(const bf16x8*)(vr + ((quad+4) ^ sw)*8);
            if (act0){
                o[0][jd] = __builtin_amdgcn_mfma_f32_16x16x32_bf16(pf[0][0], vf0, o[0][jd], 0,0,0);
                o[0][jd] = __builtin_amdgcn_mfma_f32_16x16x32_bf16(pf[0][1], vf1, o[0][jd], 0,0,0);
            }
            o[1][jd] = __builtin_amdgcn_mfma_f32_16x16x32_bf16(pf[1][0], vf0, o[1][jd], 0,0,0);
            o[1][jd] = __builtin_amdgcn_mfma_f32_16x16x32_bf16(pf[1][1], vf1, o[1][jd], 0,0,0);
        }
    }

    // l reduction over quads (disjoint key subsets per quad), epilogue
    #pragma unroll
    for (int h2 = 0; h2 < 2; ++h2){
        float ls = lsum[h2];
        ls += __shfl_xor(ls, 16, 64);
        ls += __shfl_xor(ls, 32, 64);
        float inv = __builtin_amdgcn_rcpf(ls);
        const int Rb = (h2 == 0) ? R0_0 : R0_1;
        #pragma unroll
        for (int r = 0; r < 4; ++r){
            float linv = __shfl(inv, (lane & 48) | (quad*4 + r), 64);
            int t = Rb + quad*4 + r;
            #pragma unroll
            for (int jd = 0; jd < 4; ++jd)
                ya[(((size_t)(b*TT + t))*HH + h)*HD + jd*16 + l16] = f2b(o[h2][jd][r]*linv);
        }
    }
}

// ---------------- launch ----------------------------------------------------
extern "C" void kernel_launch(void* const* d_in, const int* in_sizes, int n_in,
                              void* d_out, int out_size, void* d_ws, size_t ws_size,
                              hipStream_t stream) {
    const float* x    = (const float*)d_in[0];
    const float* w_q  = (const float*)d_in[1];
    const float* w_kv = (const float*)d_in[2];
    const float* w_c  = (const float*)d_in[3];
    const float* qw   = (const float*)d_in[4];
    const float* kw   = (const float*)d_in[5];
    float* out = (float*)d_out;

    char* ws = (char*)d_ws;
    unsigned short* xb    = (unsigned short*)(ws);                    // 16 MB
    unsigned short* wqkvb = (unsigned short*)(ws + ((size_t)16<<20)); // 3 MB
    unsigned short* wcb   = (unsigned short*)(ws + ((size_t)19<<20)); // 2 MB
    unsigned short* QKVb  = (unsigned short*)(ws + ((size_t)21<<20)); // 24 MB
    unsigned short* qa    = (unsigned short*)(ws + ((size_t)45<<20)); // 16 MB
    unsigned short* ka    = (unsigned short*)(ws + ((size_t)61<<20)); // 4 MB
    unsigned short* vat   = (unsigned short*)(ws + ((size_t)65<<20)); // 4 MB
    unsigned short* ya    = (unsigned short*)(ws + ((size_t)69<<20)); // 16 MB

    // 1) convert all inputs to bf16 (one kernel)
    cvt_all<<<dim3(2752512/256), 256, 0, stream>>>(x, w_q, w_kv, w_c, xb, wqkvb, wcb);

    // 2) fused QKV = x @ [w_q; w_kv]^T  (8192 x 1536 x 1024), bf16 out
    gemm_bt<1><<<dim3(1536/128, MM/128), 256, 0, stream>>>(xb, wqkvb, (void*)QKVb, MM, 1536, CC);

    // 3) V transpose to (b,n,d,t) bf16
    vtrans<<<dim3(TT/64, HKV, BB), 256, 0, stream>>>(QKVb, vat);

    // 4) RMSNorm + RoPE for Q,K
    norm_rope<<<dim3(MM*20/4), 256, 0, stream>>>(QKVb, qw, kw, qa, ka);

    // 5) flash attention, balanced pair-blocks
    attn_mfma<<<dim3(16, HKV, BB), 512, 0, stream>>>(qa, ka, vat, ya);

    // 6) out = y @ w_c^T (fp32 out)
    gemm_bt<0><<<dim3(CC/128, MM/128), 256, 0, stream>>>(ya, wcb, (void*)out, MM, CC, CC);
}

// Round 7
// 234.887 us; speedup vs baseline: 1.7435x; 1.1524x over previous
//
#include <hip/hip_runtime.h>
#include <math.h>

// Problem constants
#define BB 8
#define TT 1024
#define CC 1024
#define HH 16
#define HKV 4
#define HD 64
#define MM (BB*TT)   // 8192
#define LOG2E 1.4426950408889634f

typedef __attribute__((ext_vector_type(8))) short bf16x8;
typedef __attribute__((ext_vector_type(4))) float f32x4;

__device__ __forceinline__ float b2f(unsigned short x){
    union{unsigned int i; float f;} u; u.i = ((unsigned int)x)<<16; return u.f;
}
__device__ __forceinline__ unsigned short f2b(float f){
    union{float f; unsigned int i;} u; u.f = f;
    unsigned int r = u.i + 0x7fffu + ((u.i>>16)&1u);
    return (unsigned short)(r>>16);
}

// async 16B global -> LDS (gfx950 global_load_lds_dwordx4)
#define GLD16(gp, lp) __builtin_amdgcn_global_load_lds( \
    (__attribute__((address_space(1))) void*)(gp), \
    (__attribute__((address_space(3))) void*)(lp), 16, 0, 0)

// ---------------- fp32 -> bf16 conversion (all inputs, one kernel) ----------
__global__ __launch_bounds__(256) void cvt_all(const float* __restrict__ x,
                                               const float* __restrict__ w_q,
                                               const float* __restrict__ w_kv,
                                               const float* __restrict__ w_c,
                                               unsigned short* __restrict__ xb,
                                               unsigned short* __restrict__ wqkvb,
                                               unsigned short* __restrict__ wcb){
    int i = blockIdx.x*256 + threadIdx.x;
    const float* src; unsigned short* dst; int off;
    if (i < 2097152)      { src = x;    dst = xb;              off = i; }
    else if (i < 2359296) { src = w_q;  dst = wqkvb;           off = i - 2097152; }
    else if (i < 2490368) { src = w_kv; dst = wqkvb + 1048576; off = i - 2359296; }
    else                  { src = w_c;  dst = wcb;             off = i - 2490368; }
    float4 f = ((const float4*)src)[off];
    ushort4 o;
    o.x = f2b(f.x); o.y = f2b(f.y); o.z = f2b(f.z); o.w = f2b(f.w);
    ((ushort4*)dst)[off] = o;
}

// ---------------- bf16 MFMA GEMM: C = A(MxK) * Bt(NxK)^T, BK=64 -------------
// XOR-swizzled LDS (source-side permutation, GLD16 dst stays contiguous).
template<int BF16OUT>
__global__ __launch_bounds__(256) void gemm_bt(const unsigned short* __restrict__ A,
                                               const unsigned short* __restrict__ Bt,
                                               void* __restrict__ Cc,
                                               int M, int N, int K){
    __shared__ __align__(16) unsigned short As[128*64];
    __shared__ __align__(16) unsigned short Bs[128*64];
    const int tid  = threadIdx.x;
    const int wid  = tid >> 6;
    const int lane = tid & 63;
    const int wm   = wid >> 1;
    const int wn   = wid & 1;
    const int l16  = lane & 15;
    const int quad = lane >> 4;
    const int bm = blockIdx.y * 128;
    const int bn = blockIdx.x * 128;

    const unsigned short* ga[4]; const unsigned short* gb[4];
    char* la[4]; char* lb[4];
    {
        int rbase = tid >> 3, c_lds = tid & 7;
        #pragma unroll
        for (int it = 0; it < 4; ++it){
            int row = it*32 + rbase;
            int cg  = c_lds ^ (row & 7);
            ga[it] = A  + (size_t)(bm+row)*K + cg*8;
            gb[it] = Bt + (size_t)(bn+row)*K + cg*8;
            la[it] = (char*)As + (size_t)(it*256 + tid)*16;
            lb[it] = (char*)Bs + (size_t)(it*256 + tid)*16;
        }
    }

    f32x4 acc[4][4] = {};

    for (int k0 = 0; k0 < K; k0 += 64){
        __syncthreads();
        #pragma unroll
        for (int it = 0; it < 4; ++it){
            GLD16(ga[it] + k0, la[it]);
            GLD16(gb[it] + k0, lb[it]);
        }
        __syncthreads();

        #pragma unroll
        for (int kh = 0; kh < 2; ++kh){
            bf16x8 af[4], bfr[4];
            #pragma unroll
            for (int i = 0; i < 4; ++i){
                int row = wm*64 + i*16 + l16;
                int ch  = (kh*4 + quad) ^ (row & 7);
                af[i] = *(const bf16x8*)(As + row*64 + ch*8);
            }
            #pragma unroll
            for (int j = 0; j < 4; ++j){
                int row = wn*64 + j*16 + l16;
                int ch  = (kh*4 + quad) ^ (row & 7);
                bfr[j] = *(const bf16x8*)(Bs + row*64 + ch*8);
            }
            #pragma unroll
            for (int i = 0; i < 4; ++i)
                #pragma unroll
                for (int j = 0; j < 4; ++j)
                    acc[i][j] = __builtin_amdgcn_mfma_f32_16x16x32_bf16(af[i], bfr[j], acc[i][j], 0, 0, 0);
        }
    }

    #pragma unroll
    for (int i = 0; i < 4; ++i){
        int row0 = wm*64 + i*16 + quad*4;
        #pragma unroll
        for (int j = 0; j < 4; ++j){
            int col = bn + wn*64 + j*16 + l16;
            #pragma unroll
            for (int r = 0; r < 4; ++r){
                if (BF16OUT)
                    ((unsigned short*)Cc)[(size_t)(bm + row0 + r)*N + col] = f2b(acc[i][j][r]);
                else
                    ((float*)Cc)[(size_t)(bm + row0 + r)*N + col] = acc[i][j][r];
            }
        }
    }
}

// ---------------- RMSNorm + RoPE for K only ---------------------------------
// QKVb row stride 1536: K at cols 1024..1279. One wave per (row, kv-head).
__global__ __launch_bounds__(256) void norm_rope_k(const unsigned short* __restrict__ QKVb,
                                                   const float* __restrict__ kw,
                                                   unsigned short* __restrict__ ka){
    int row  = blockIdx.x;
    int u    = threadIdx.x >> 6;
    int lane = threadIdx.x & 63;
    int b = row >> 10;
    int t = row & 1023;

    float val = b2f(QKVb[(size_t)row*1536 + 1024 + u*64 + lane]);

    float ss = val*val;
    #pragma unroll
    for (int off = 32; off > 0; off >>= 1) ss += __shfl_xor(ss, off, 64);
    float normed = val * rsqrtf(ss*(1.0f/64.0f) + 1e-6f) * kw[lane];

    int i = lane & 31;
    float freq = (float)t * exp2f(-(float)i * (13.287712379549449f/32.0f));
    float s, c;
    sincosf(freq, &s, &c);
    float other = __shfl_xor(normed, 32, 64);
    float outv = (lane < 32) ? (normed*c + other*s) : (-other*s + normed*c);

    ka[(((size_t)(b*HKV + u))*TT + t)*HD + lane] = f2b(outv);
}

// ---------------- V transpose: QKVb bf16 -> vat bf16 (b,n,d,t) --------------
__global__ __launch_bounds__(256) void vtrans(const unsigned short* __restrict__ QKVb,
                                              unsigned short* __restrict__ vat){
    __shared__ unsigned short tile[64][72];
    const int tid = threadIdx.x;
    const int tblk = blockIdx.x, n = blockIdx.y, b = blockIdx.z;
    #pragma unroll
    for (int it = 0; it < 2; ++it){
        int i = it*256 + tid;           // 0..511 chunks of 8 bf16
        int r = i >> 3, c = i & 7;
        uint4 v = *(const uint4*)(QKVb + ((size_t)(b*TT + tblk*64 + r))*1536 + 1280 + n*64 + c*8);
        *(uint4*)(&tile[r][c*8]) = v;
    }
    __syncthreads();
    const int d = tid >> 2, tseg = tid & 3;
    unsigned short tmp[16];
    #pragma unroll
    for (int i = 0; i < 16; ++i) tmp[i] = tile[tseg*16 + i][d];
    size_t off = (((size_t)(b*HKV + n))*HD + d)*TT + tblk*64 + tseg*16;
    *(uint4*)(vat + off)     = *(const uint4*)tmp;
    *(uint4*)(vat + off + 8) = *(const uint4*)(tmp + 8);
}

// ---------------- Flash attention: XCD-clustered pair-blocks, fused Q-norm --
// Grid (4,8,16): n=bx, b=by, iz=bz. Linear id c = n+4b+32*iz -> all 16 blocks
// of one (n,b) K/V stream share c mod 8 (same XCD -> L2-served staging).
// Pair map ib = iz<8 ? iz : 23-iz makes c and c+256 (same CU at 2 blk/CU)
// complementary in tile count. Each wave: 1 head x 2 16-row q-windows.
// Q RMSNorm+RoPE fused in preamble (q-row consumed by exactly this wave).
// Fixed-cap softmax: p = exp(cap-50) in [e^-100, 1].
__global__ __launch_bounds__(512, 4) void attn_mfma(const unsigned short* __restrict__ QKVb,
                                                    const unsigned short* __restrict__ ka,
                                                    const unsigned short* __restrict__ vat,
                                                    const float* __restrict__ qw,
                                                    unsigned short* __restrict__ ya){
    __shared__ __align__(16) unsigned short Ks[64*64];    // [key][chunk^(key&7)]
    __shared__ __align__(16) unsigned short Vts[64*64];   // [d][chunk^(d&7)]
    __shared__ __align__(16) unsigned short Ps[8][32*72]; // per-wave [q32][key]

    const int tid = threadIdx.x;
    const int wave = tid >> 6, lane = tid & 63;
    const int l16 = lane & 15, quad = lane >> 4;
    const int n = blockIdx.x, b = blockIdx.y, iz = blockIdx.z;
    const int ib = (iz < 8) ? iz : 23 - iz;    // complementary pairing
    const int head = wave & 3, sub = wave >> 2;
    const int h = n*4 + head;
    const int R0[2] = { ib*32 + sub*16, (31-ib)*32 + sub*16 };

    // ---- fused Q RMSNorm + RoPE preamble ----
    bf16x8 qf[2][2];
    {
        float invf[8], rw0[8], rw1[8];
        #pragma unroll
        for (int j = 0; j < 8; ++j){
            int i = quad*8 + j;
            invf[j] = exp2f(-(float)i * (13.287712379549449f/32.0f));
            rw0[j] = qw[i]; rw1[j] = qw[i + 32];
        }
        #pragma unroll
        for (int h2 = 0; h2 < 2; ++h2){
            const int t = R0[h2] + l16;
            const unsigned short* qp = QKVb + ((size_t)(b*TT + t))*1536 + h*64 + quad*8;
            float x0[8], x1[8];
            {
                uint4 a = *(const uint4*)qp;
                uint4 c = *(const uint4*)(qp + 32);
                const unsigned short* pa = (const unsigned short*)&a;
                const unsigned short* pc = (const unsigned short*)&c;
                #pragma unroll
                for (int j = 0; j < 8; ++j){ x0[j] = b2f(pa[j]); x1[j] = b2f(pc[j]); }
            }
            float ss = 0.f;
            #pragma unroll
            for (int j = 0; j < 8; ++j) ss += x0[j]*x0[j] + x1[j]*x1[j];
            ss += __shfl_xor(ss, 16, 64);
            ss += __shfl_xor(ss, 32, 64);
            float rn = rsqrtf(ss*(1.0f/64.0f) + 1e-6f);
            unsigned short o0[8], o1[8];
            #pragma unroll
            for (int j = 0; j < 8; ++j){
                float s, c;
                sincosf((float)t * invf[j], &s, &c);
                float n0 = x0[j]*rn*rw0[j];
                float n1 = x1[j]*rn*rw1[j];
                o0[j] = f2b(n0*c + n1*s);
                o1[j] = f2b(n1*c - n0*s);
            }
            qf[h2][0] = *(const bf16x8*)o0;
            qf[h2][1] = *(const bf16x8*)o1;
        }
    }

    const unsigned short* kbase = ka  + ((size_t)(b*HKV + n))*TT*HD;
    const unsigned short* vbase = vat + ((size_t)(b*HKV + n))*HD*TT;

    // staging: each thread stages one 16B K chunk and one 16B V chunk
    const unsigned short* gk; const unsigned short* gv;
    char* lk; char* lv;
    {
        int row = tid >> 3, slot = tid & 7;
        int cg = slot ^ (row & 7);
        gk = kbase + (size_t)row*HD + cg*8;
        gv = vbase + (size_t)row*TT + cg*8;
        lk = (char*)Ks  + (size_t)tid*16;
        lv = (char*)Vts + (size_t)tid*16;
    }

    float lsum[2] = {0.f, 0.f};
    f32x4 o[2][4] = {};
    unsigned short* PsW = &Ps[wave][0];

    const float C1 = 0.125f * 0.04f * LOG2E;   // raw -> exponent of e^{2s/50}
    const float C2 = -100.0f * LOG2E;          // p = exp2(C2 * w)
    const int sw = l16 & 7;
    const int ktmax = (1023 - 32*ib) >> 6;

    for (int kt = 0; kt <= ktmax; ++kt){
        const int k0 = kt*64;
        __syncthreads();
        GLD16(gk + (size_t)k0*HD, lk);
        GLD16(gv + k0, lv);
        __syncthreads();

        const bool act0 = (k0 <= R0[0] + 15);
        // S^T = K Q^T : D[m=key][n=q]; key = j*16+quad*4+r, q = l16
        f32x4 sacc[2][4];
        #pragma unroll
        for (int j = 0; j < 4; ++j){
            const unsigned short* kr = Ks + (j*16 + l16)*64;
            bf16x8 kf0 = *(const bf16x8*)(kr + (quad ^ sw)*8);
            bf16x8 kf1 = *(const bf16x8*)(kr + ((quad+4) ^ sw)*8);
            if (act0){
                f32x4 z = {};
                z = __builtin_amdgcn_mfma_f32_16x16x32_bf16(kf0, qf[0][0], z, 0,0,0);
                sacc[0][j] = __builtin_amdgcn_mfma_f32_16x16x32_bf16(kf1, qf[0][1], z, 0,0,0);
            }
            {
                f32x4 z = {};
                z = __builtin_amdgcn_mfma_f32_16x16x32_bf16(kf0, qf[1][0], z, 0,0,0);
                sacc[1][j] = __builtin_amdgcn_mfma_f32_16x16x32_bf16(kf1, qf[1][1], z, 0,0,0);
            }
        }
        // softmax + P write per window
        #pragma unroll
        for (int h2 = 0; h2 < 2; ++h2){
            if (h2 == 0 && !act0) continue;
            const int Rb = R0[h2];
            const bool full = (k0 + 63 <= Rb);
            const int qrow = Rb + l16;
            #pragma unroll
            for (int j = 0; j < 4; ++j){
                unsigned int pu[4];
                #pragma unroll
                for (int r = 0; r < 4; ++r){
                    float e = exp2f(sacc[h2][j][r]*C1);
                    float w = __builtin_amdgcn_rcpf(e + 1.f);
                    float p = exp2f(C2*w);
                    if (!full && (k0 + j*16 + quad*4 + r > qrow)) p = 0.f;
                    union{float f; unsigned int u;} cv; cv.f = p;
                    unsigned int pt = cv.u & 0xffff0000u;   // truncate to bf16
                    cv.u = pt;
                    lsum[h2] += cv.f;                       // l consistent with P
                    pu[r] = pt;
                }
                unsigned int pk0 = __builtin_amdgcn_perm(pu[1], pu[0], 0x07060302u);
                unsigned int pk1 = __builtin_amdgcn_perm(pu[3], pu[2], 0x07060302u);
                *(uint2*)(PsW + (h2*16 + l16)*72 + j*16 + quad*4) = make_uint2(pk0, pk1);
            }
        }
        // PV: A = P[q][key], B = Vt[d][key]; vf shared across both windows
        bf16x8 pf[2][2];
        if (act0){
            pf[0][0] = *(const bf16x8*)(PsW + l16*72 + quad*8);
            pf[0][1] = *(const bf16x8*)(PsW + l16*72 + quad*8 + 32);
        }
        pf[1][0] = *(const bf16x8*)(PsW + (16 + l16)*72 + quad*8);
        pf[1][1] = *(const bf16x8*)(PsW + (16 + l16)*72 + quad*8 + 32);
        #pragma unroll
        for (int jd = 0; jd < 4; ++jd){
            const unsigned short* vr = Vts + (jd*16 + l16)*64;
            bf16x8 vf0 = *(const bf16x8*)(vr + (quad ^ sw)*8);
            bf16x8 vf1 = *(const bf16x8*)(vr + ((quad+4) ^ sw)*8);
            if (act0){
                o[0][jd] = __builtin_amdgcn_mfma_f32_16x16x32_bf16(pf[0][0], vf0, o[0][jd], 0,0,0);
                o[0][jd] = __builtin_amdgcn_mfma_f32_16x16x32_bf16(pf[0][1], vf1, o[0][jd], 0,0,0);
            }
            o[1][jd] = __builtin_amdgcn_mfma_f32_16x16x32_bf16(pf[1][0], vf0, o[1][jd], 0,0,0);
            o[1][jd] = __builtin_amdgcn_mfma_f32_16x16x32_bf16(pf[1][1], vf1, o[1][jd], 0,0,0);
        }
    }

    // l reduction over quads (disjoint key subsets per quad), epilogue
    #pragma unroll
    for (int h2 = 0; h2 < 2; ++h2){
        float ls = lsum[h2];
        ls += __shfl_xor(ls, 16, 64);
        ls += __shfl_xor(ls, 32, 64);
        float inv = __builtin_amdgcn_rcpf(ls);
        const int Rb = R0[h2];
        #pragma unroll
        for (int r = 0; r < 4; ++r){
            float linv = __shfl(inv, (lane & 48) | (quad*4 + r), 64);
            int t = Rb + quad*4 + r;
            #pragma unroll
            for (int jd = 0; jd < 4; ++jd)
                ya[(((size_t)(b*TT + t))*HH + h)*HD + jd*16 + l16] = f2b(o[h2][jd][r]*linv);
        }
    }
}

// ---------------- launch ----------------------------------------------------
extern "C" void kernel_launch(void* const* d_in, const int* in_sizes, int n_in,
                              void* d_out, int out_size, void* d_ws, size_t ws_size,
                              hipStream_t stream) {
    const float* x    = (const float*)d_in[0];
    const float* w_q  = (const float*)d_in[1];
    const float* w_kv = (const float*)d_in[2];
    const float* w_c  = (const float*)d_in[3];
    const float* qw   = (const float*)d_in[4];
    const float* kw   = (const float*)d_in[5];
    float* out = (float*)d_out;

    char* ws = (char*)d_ws;
    unsigned short* xb    = (unsigned short*)(ws);                    // 16 MB
    unsigned short* wqkvb = (unsigned short*)(ws + ((size_t)16<<20)); // 3 MB
    unsigned short* wcb   = (unsigned short*)(ws + ((size_t)19<<20)); // 2 MB
    unsigned short* QKVb  = (unsigned short*)(ws + ((size_t)21<<20)); // 24 MB
    unsigned short* ka    = (unsigned short*)(ws + ((size_t)45<<20)); // 4 MB
    unsigned short* vat   = (unsigned short*)(ws + ((size_t)49<<20)); // 4 MB
    unsigned short* ya    = (unsigned short*)(ws + ((size_t)53<<20)); // 16 MB

    // 1) convert all inputs to bf16 (one kernel)
    cvt_all<<<dim3(2752512/256), 256, 0, stream>>>(x, w_q, w_kv, w_c, xb, wqkvb, wcb);

    // 2) fused QKV = x @ [w_q; w_kv]^T  (8192 x 1536 x 1024), bf16 out
    gemm_bt<1><<<dim3(1536/128, MM/128), 256, 0, stream>>>(xb, wqkvb, (void*)QKVb, MM, 1536, CC);

    // 3) V transpose to (b,n,d,t) bf16
    vtrans<<<dim3(TT/64, HKV, BB), 256, 0, stream>>>(QKVb, vat);

    // 4) RMSNorm + RoPE for K only (Q fused into attention)
    norm_rope_k<<<dim3(MM), 256, 0, stream>>>(QKVb, kw, ka);

    // 5) flash attention (XCD-clustered, paired, fused Q-norm)
    attn_mfma<<<dim3(HKV, BB, 16), 512, 0, stream>>>(QKVb, ka, vat, qw, ya);

    // 6) out = y @ w_c^T (fp32 out)
    gemm_bt<0><<<dim3(CC/128, MM/128), 256, 0, stream>>>(ya, wcb, (void*)out, MM, CC, CC);
}